// Round 8
// baseline (259.576 us; speedup 1.0000x reference)
//
#include <hip/hip_runtime.h>
#include <hip/hip_cooperative_groups.h>
#include <math.h>

// FFTChainMatrix, single cooperative kernel.
//   stage0: 64-entry trig table in LDS.
//   stage1: each block builds 16 of 4096 Bf (o,i)-pairs -> global Bf.
//   stage2: DFT-basis MFMA fragments built in-register from trig (no Dt/E
//           global tables, no prep kernel).
//   phase A: XF = rfft_64(x)  (HBM reads, MFMA K=64, scatter to LDS)
//   -- threadfence + grid.sync (Bf visible device-wide) --
//   phase B: per f, YF = XF . Bf[f]^T in place in LDS (v1-exact)
//   phase C: y = E . YF, E frags built from trig       (v1-exact)
// v8: v1 (65.5us fused, best) + prep merged in via cooperative launch.
// Lesson from v7: __launch_bounds__ 2nd arg acts as min-BLOCKS/CU on this
// toolchain ((512,2) capped VGPR at 128 -> 53MB spill traffic). Plain
// __launch_bounds__(512) = v1's no-spill regime.

namespace cg = cooperative_groups;

typedef unsigned short u16;
typedef unsigned int   u32;
typedef __attribute__((ext_vector_type(8))) short bf16x8;
typedef __attribute__((ext_vector_type(4))) float f32x4;

#define TWO_PI 6.2831853071795864769f
#define SF 2056                          // u16 per f-slice (16*128 + 8 pad)

__device__ __forceinline__ u16 f2bf(float f) {   // RNE fp32 -> bf16
    union { float f; unsigned u; } v; v.f = f;
    unsigned r = v.u + 0x7FFFu + ((v.u >> 16) & 1u);
    return (u16)(r >> 16);
}

__global__ __launch_bounds__(512) void fused_all(const float* __restrict__ x,
                                                 const float* __restrict__ p,
                                                 const float* __restrict__ cw,
                                                 u16* __restrict__ Bf,
                                                 float* __restrict__ y) {
    __shared__ u16    sm[33 * SF];       // 135,696 B
    __shared__ float2 trig[64];          //     512 B
    __shared__ float  ctw[8][2][64];     //   4,096 B  (total 140,304)
    const int tid = threadIdx.x, lane = tid & 63, wave = tid >> 6;
    const int lm = lane & 15, q = lane >> 4, kq8 = q * 8, r0 = q * 4;
    const float* xb = x + (size_t)blockIdx.x * 65536u;   // 16 tok * 4096

    // ---- stage 0: trig table --------------------------------------------
    if (tid < 64) {
        float s, c;
        sincosf(TWO_PI * (float)tid * (1.f / 64.f), &s, &c);
        trig[tid] = make_float2(s, c);
    }
    __syncthreads();

    // ---- stage 1: Bf build (16 pairs/block, 2 per wave; exact prep math) --
#pragma unroll
    for (int p2 = 0; p2 < 2; ++p2) {
        const int pg = blockIdx.x * 16 + wave * 2 + p2;   // 0..4095
        const int o = pg >> 6, i = pg & 63;
        const float* base = p + (size_t)o * 4096 + i * 64 + lane;
        ctw[wave][p2][lane] = cw[0] * base[0]      + cw[1] * base[262144]
                            + cw[2] * base[524288] + cw[3] * base[786432];
    }
    __syncthreads();
#pragma unroll
    for (int p2 = 0; p2 < 2; ++p2) {
        const int pg = blockIdx.x * 16 + wave * 2 + p2;
        const int o = pg >> 6, i = pg & 63;
        if (lane < 33) {                  // f = lane
            float cr = 0.f, ci = 0.f;
            for (int u = 0; u < 64; ++u) {
                float2 sc = trig[(lane * u) & 63];
                float t = ctw[wave][p2][u];
                cr += t * sc.y; ci -= t * sc.x;
            }
            u16* b = Bf + (size_t)lane * 16384 + (2 * o) * 128 + 2 * i;
            b[0]   = f2bf(cr);  b[1]   = f2bf(-ci);
            b[128] = f2bf(ci);  b[129] = f2bf(cr);
        }
    }

    // ---- stage 2: DFT basis frags from trig (replaces Dt global) ---------
    bf16x8 bfr[2][5];
#pragma unroll
    for (int kt = 0; kt < 2; ++kt)
#pragma unroll
        for (int ni = 0; ni < 5; ++ni) {
            const int n = ni * 16 + lm, f = n >> 1, par = n & 1;
            union { u16 u[8]; bf16x8 v; } pk;
#pragma unroll
            for (int j = 0; j < 8; ++j) {
                const int k = kt * 32 + kq8 + j;
                float v = 0.f;
                if (n < 66) {
                    float2 sc = trig[(f * k) & 63];
                    v = par ? -sc.x : sc.y;
                }
                pk.u[j] = f2bf(v);
            }
            bfr[kt][ni] = pk.v;
        }

    // ---- phase A: DFT (v1-exact, 2 passes of 8 tokens) --------------------
#pragma unroll
    for (int pass = 0; pass < 2; ++pass) {
        f32x4 acc[4][5];
#pragma unroll
        for (int mi = 0; mi < 4; ++mi)
#pragma unroll
            for (int ni = 0; ni < 5; ++ni) acc[mi][ni] = (f32x4){0.f,0.f,0.f,0.f};
#pragma unroll
        for (int kt = 0; kt < 2; ++kt) {
#pragma unroll
            for (int mi = 0; mi < 4; ++mi) {
                const int row = wave*128 + pass*64 + mi*16 + lm;  // (tok,i)
                const float* rp = xb + row*64 + kt*32 + kq8;
                float4 p0 = *(const float4*)rp;
                float4 p1 = *(const float4*)(rp + 4);
                union { u16 u[8]; bf16x8 v; } pk;
                pk.u[0]=f2bf(p0.x); pk.u[1]=f2bf(p0.y);
                pk.u[2]=f2bf(p0.z); pk.u[3]=f2bf(p0.w);
                pk.u[4]=f2bf(p1.x); pk.u[5]=f2bf(p1.y);
                pk.u[6]=f2bf(p1.z); pk.u[7]=f2bf(p1.w);
#pragma unroll
                for (int ni = 0; ni < 5; ++ni)
                    acc[mi][ni] = __builtin_amdgcn_mfma_f32_16x16x32_bf16(
                        pk.v, bfr[kt][ni], acc[mi][ni], 0, 0, 0);
            }
        }
        // scatter C into XF slices (bf16), XOR row-swizzle
        const int tok = wave*2 + pass;
        const int sw  = (tok & 7) << 3;
#pragma unroll
        for (int mi = 0; mi < 4; ++mi)
#pragma unroll
            for (int ni = 0; ni < 5; ++ni) {
                const int col = ni*16 + lm;
                if (col < 66) {
                    const int f = col >> 1, par = col & 1;
                    f32x4 v = acc[mi][ni];
#pragma unroll
                    for (int r = 0; r < 4; ++r) {
                        int ii = mi*16 + r0 + r;
                        sm[f*SF + tok*128 + (((ii<<1)|par) ^ sw)] = f2bf(v[r]);
                    }
                }
            }
    }

    // ---- Bf visible device-wide; all blocks' XF ready ---------------------
    __threadfence();
    cg::this_grid().sync();

    // ---- phase B: per f, YF = XF . Bf[f]^T, in place (v1-exact) -----------
    for (int f = wave; f < 33; f += 8) {
        u16* sl = &sm[f * SF];
        const u16* Bff = Bf + (size_t)f * 16384;
        bf16x8 af[4];                       // full A (M=16 tokens) in regs
#pragma unroll
        for (int ks = 0; ks < 4; ++ks)
            af[ks] = *(const bf16x8*)&sl[lm*128 + ((ks*32 + kq8) ^ ((lm&7)<<3))];
#pragma unroll
        for (int nt = 0; nt < 8; ++nt) {
            f32x4 c = (f32x4){0.f,0.f,0.f,0.f};
#pragma unroll
            for (int ks = 0; ks < 4; ++ks) {  // Bf fragments straight from L2
                bf16x8 bq = *(const bf16x8*)&Bff[(nt*16 + lm)*128 + ks*32 + kq8];
                c = __builtin_amdgcn_mfma_f32_16x16x32_bf16(af[ks], bq, c, 0, 0, 0);
            }
#pragma unroll
            for (int r = 0; r < 4; ++r) {     // write-back: cols nt*16+lm
                int tok = r0 + r;
                sl[tok*128 + ((nt*16 + lm) ^ ((tok&7)<<3))] = f2bf(c[r]);
            }
        }
    }
    __syncthreads();

    // ---- phase C: iDFT basis frags from trig, then v1-exact ---------------
    bf16x8 ef[3][4];
#pragma unroll
    for (int kt = 0; kt < 3; ++kt)
#pragma unroll
        for (int mt = 0; mt < 4; ++mt) {
            const int t = mt * 16 + lm;
            union { u16 u[8]; bf16x8 v; } pk;
#pragma unroll
            for (int j = 0; j < 8; ++j) {
                const int k = kt * 32 + kq8 + j;
                float v = 0.f;
                if (k < 66) {
                    const int f = k >> 1;
                    const float wf = (f == 0 || f == 32) ? 1.f : 2.f;
                    float2 sc = trig[(f * t) & 63];
                    v = (wf * (1.f / 64.f)) * ((k & 1) ? -sc.x : sc.y);
                }
                pk.u[j] = f2bf(v);
            }
            ef[kt][mt] = pk.v;
        }
#pragma unroll
    for (int nt = 0; nt < 8; ++nt) {          // 2 tokens x 64 o per wave
        const int tokL = wave*2 + (nt >> 2);
        const int o = (nt & 3)*16 + lm;
        const int cb = tokL*128 + ((2*o) ^ ((tokL&7)<<3));
        f32x4 acc[4];
#pragma unroll
        for (int mt = 0; mt < 4; ++mt) acc[mt] = (f32x4){0.f,0.f,0.f,0.f};
#pragma unroll
        for (int kt = 0; kt < 3; ++kt) {
            union { u32 w[4]; bf16x8 v; } bq;  // (re,im) pairs across f slices
#pragma unroll
            for (int j = 0; j < 4; ++j) {
                int f = kt*16 + q*4 + j;
                u32 vv = 0u;
                if (f < 33) vv = *(const u32*)&sm[f*SF + cb];
                bq.w[j] = vv;
            }
#pragma unroll
            for (int mt = 0; mt < 4; ++mt)
                acc[mt] = __builtin_amdgcn_mfma_f32_16x16x32_bf16(
                    ef[kt][mt], bq.v, acc[mt], 0, 0, 0);
        }
        float* yb = y + ((size_t)(blockIdx.x*16 + tokL))*4096 + o*64;
#pragma unroll
        for (int mt = 0; mt < 4; ++mt) {       // 4 consecutive t per lane
            float4 st = { acc[mt][0], acc[mt][1], acc[mt][2], acc[mt][3] };
            *(float4*)&yb[mt*16 + r0] = st;
        }
    }
}

extern "C" void kernel_launch(void* const* d_in, const int* in_sizes, int n_in,
                              void* d_out, int out_size, void* d_ws, size_t ws_size,
                              hipStream_t stream) {
    const float* x      = (const float*)d_in[0];  // (2,2048,4096) fp32
    const float* params = (const float*)d_in[1];  // (4,64,64,64)  fp32
    const float* cw     = (const float*)d_in[2];  // (4,)          fp32
    float* out = (float*)d_out;
    u16* Bf = (u16*)d_ws;                         // 33*128*128 u16 = 1.03 MB

    void* args[] = { (void*)&x, (void*)&params, (void*)&cw,
                     (void*)&Bf, (void*)&out };
    hipLaunchCooperativeKernel((const void*)fused_all, dim3(256), dim3(512),
                               args, 0, stream);
}

// Round 9
// 208.438 us; speedup vs baseline: 1.2453x; 1.2453x over previous
//
#include <hip/hip_runtime.h>
#include <math.h>

// FFTChainMatrix, fused frequency-domain factorization with an intra-block
// 2-tile software pipeline.
//   prep : build Bf (33 x 128 x 128 spectral operator), Dt2, E2 tables.
//   fused: 256 blocks x 512 thr (8 waves), 16 tokens = 2 tiles x 8 tokens,
//          LDS split in two 68KB halves (one per tile):
//     A_k: DFT of tile k        (HBM reads, MFMA K=64, scatter to sm[k])
//     B_k: per-f YF=XF.Bf^T     (L2 reads, M=8 MFMA, in place in sm[k])
//     C_k: iDFT + y stores      (LDS gather, MFMA, HBM writes)
//   schedule: A0 | B0 + A1-loads-in-flight | C0 + B1 (stores drain under L2)
//             | C1.
// v9 = v7 source with ONE change: __launch_bounds__(512,2) -> (512,1).
// Round-7 evidence: the 2nd arg is min-BLOCKS/CU on this toolchain
// ((512,4)->VGPR64, (512,2)->VGPR128). v7's 128-cap forced ~53MB of scratch
// spill (FETCH 37->63MB, WRITE 65->93MB) and poisoned the pipeline test.
// At 512 thr / 1 block/CU, VGPR<=256 costs no occupancy (waves halve only
// at 64/128/256), so (512,1) frees the full 256-reg budget.

typedef unsigned short u16;
typedef unsigned int   u32;
typedef __attribute__((ext_vector_type(8))) short bf16x8;
typedef __attribute__((ext_vector_type(4))) float f32x4;

#define TWO_PI 6.2831853071795864769f

#define SF 1032                          // u16 per f-slice (8*128 + 8 pad)
#define TILE_ELEMS (33u * SF)            // 34056 u16 = 68112 B per tile
#define BF_ELEMS (33u*128u*128u)         // 540672 u16
#define DT_OFF   BF_ELEMS
#define DT_ELEMS (2u*4u*80u*8u)          // 5120  : [kt][q][n(80)][8]
#define E_OFF    (DT_OFF + DT_ELEMS)
#define E_ELEMS  (3u*4u*64u*8u)          // 6144  : [kt][q][t(64)][8]

__device__ __forceinline__ u16 f2bf(float f) {   // RNE fp32 -> bf16
    union { float f; unsigned u; } v; v.f = f;
    unsigned r = v.u + 0x7FFFu + ((v.u >> 16) & 1u);
    return (u16)(r >> 16);
}

// ---- prep: block 0 -> Dt2/E2 tables; blocks 1..1024 -> Bf ------------------
__global__ void prep(const float* __restrict__ p, const float* __restrict__ cw,
                     u16* __restrict__ Bf, u16* __restrict__ Dt, u16* __restrict__ E) {
    const int tid = threadIdx.x;
    if (blockIdx.x == 0) {
        for (int e = tid; e < (int)DT_ELEMS; e += 256) {
            int j = e & 7, rowid = e >> 3;
            int n = rowid % 80, grp = rowid / 80;          // grp = kt*4+q
            int k = (grp >> 2) * 32 + (grp & 3) * 8 + j;
            float v = 0.f;
            if (n < 66) {
                int f = n >> 1;
                float ang = TWO_PI * (float)((f * k) & 63) * (1.f / 64.f);
                v = (n & 1) ? -sinf(ang) : cosf(ang);
            }
            Dt[e] = f2bf(v);
        }
        for (int e = tid; e < (int)E_ELEMS; e += 256) {
            int j = e & 7, rowid = e >> 3;
            int t = rowid % 64, grp = rowid / 64;          // grp = kt*4+q
            int k = (grp >> 2) * 32 + (grp & 3) * 8 + j;
            float v = 0.f;
            if (k < 66) {
                int f = k >> 1;
                float wf = (f == 0 || f == 32) ? 1.f : 2.f;
                float ang = TWO_PI * (float)((f * t) & 63) * (1.f / 64.f);
                v = (wf * (1.f / 64.f)) * ((k & 1) ? -sinf(ang) : cosf(ang));
            }
            E[e] = f2bf(v);
        }
        return;
    }
    __shared__ float  ct[4][64];
    __shared__ float2 trig[64];
    const int pr = tid >> 6, ln = tid & 63;
    if (tid < 64) {
        float s, c;
        sincosf(TWO_PI * (float)tid * (1.f / 64.f), &s, &c);
        trig[tid] = make_float2(s, c);
    }
    const int pg = (blockIdx.x - 1) * 4 + pr;     // 0..4095
    const int o = pg >> 6, i = pg & 63;
    {
        const float* base = p + (size_t)o * 4096 + i * 64 + ln;
        ct[pr][ln] = cw[0] * base[0]      + cw[1] * base[262144]
                   + cw[2] * base[524288] + cw[3] * base[786432];
    }
    __syncthreads();
    if (ln < 33) {        // f = ln
        float cr = 0.f, ci = 0.f;
        for (int u = 0; u < 64; ++u) {
            float2 sc = trig[(ln * u) & 63];
            cr += ct[pr][u] * sc.y; ci -= ct[pr][u] * sc.x;
        }
        u16* b = Bf + (size_t)ln * 16384 + (2 * o) * 128 + 2 * i;
        b[0]   = f2bf(cr);  b[1]   = f2bf(-ci);
        b[128] = f2bf(ci);  b[129] = f2bf(cr);
    }
}

// ---- fused: 2-tile pipelined DFT -> per-f GEMM -> iDFT ---------------------
__global__ __launch_bounds__(512, 1) void fused(const float* __restrict__ x,
                                                const u16* __restrict__ Dt,
                                                const u16* __restrict__ Bf,
                                                const u16* __restrict__ E2,
                                                float* __restrict__ y) {
    __shared__ u16 sm[2 * TILE_ELEMS];   // 136,224 B -> 1 block/CU
    const int tid = threadIdx.x, lane = tid & 63, wave = tid >> 6;
    const int lm = lane & 15, q = lane >> 4, kq8 = q * 8, r0 = q * 4;
    const float* xb = x + (size_t)blockIdx.x * 65536u;   // 16 tok * 4096

#define LOADX(XV, tile)                                                      \
    _Pragma("unroll") for (int kt = 0; kt < 2; ++kt)                         \
    _Pragma("unroll") for (int mi = 0; mi < 4; ++mi) {                       \
        const float* rp = xb + (tile)*32768 + (wave*64 + mi*16 + lm)*64      \
                             + kt*32 + kq8;                                  \
        XV[kt][mi][0] = *(const float4*)rp;                                  \
        XV[kt][mi][1] = *(const float4*)(rp + 4);                            \
    }
#define A_MFMA(XV, ACC)                                                      \
    _Pragma("unroll") for (int kt = 0; kt < 2; ++kt)                         \
    _Pragma("unroll") for (int mi = 0; mi < 4; ++mi) {                       \
        union { u16 u[8]; bf16x8 v; } pk;                                    \
        float4 p0 = XV[kt][mi][0], p1 = XV[kt][mi][1];                       \
        pk.u[0]=f2bf(p0.x); pk.u[1]=f2bf(p0.y);                              \
        pk.u[2]=f2bf(p0.z); pk.u[3]=f2bf(p0.w);                              \
        pk.u[4]=f2bf(p1.x); pk.u[5]=f2bf(p1.y);                              \
        pk.u[6]=f2bf(p1.z); pk.u[7]=f2bf(p1.w);                              \
        _Pragma("unroll") for (int ni = 0; ni < 5; ++ni)                     \
            ACC[mi][ni] = __builtin_amdgcn_mfma_f32_16x16x32_bf16(           \
                pk.v, bfr[kt][ni], ACC[mi][ni], 0, 0, 0);                    \
    }
#define SCATTER(ACC, base)                                                   \
    {   const int sw = wave << 3;  /* tok == wave, < 8 */                    \
        _Pragma("unroll") for (int mi = 0; mi < 4; ++mi)                     \
        _Pragma("unroll") for (int ni = 0; ni < 5; ++ni) {                   \
            const int col = ni*16 + lm;                                      \
            if (col < 66) {                                                  \
                const int f = col >> 1, par = col & 1;                       \
                f32x4 v = ACC[mi][ni];                                       \
                _Pragma("unroll") for (int r = 0; r < 4; ++r) {              \
                    int ii = mi*16 + r0 + r;                                 \
                    sm[(base) + f*SF + wave*128 + (((ii<<1)|par) ^ sw)]      \
                        = f2bf(v[r]);                                        \
                }                                                            \
            }                                                                \
        }                                                                    \
    }
// phase B main (f<32), M=8 (rows dup), Bf frags double-buffered from L2
#define PHASE_B(base)                                                        \
    _Pragma("unroll") for (int t = 0; t < 4; ++t) {                          \
        const int f = t*8 + wave;                                            \
        u16* sl = &sm[(base) + f * SF];                                      \
        const u16* Bff = Bf + (size_t)f * 16384;                             \
        bf16x8 af[4];                                                        \
        _Pragma("unroll") for (int ks = 0; ks < 4; ++ks)                     \
            af[ks] = *(const bf16x8*)&sl[(lm&7)*128                          \
                                         + ((ks*32 + kq8) ^ ((lm&7)<<3))];  \
        bf16x8 bc[4], bn[4];                                                 \
        _Pragma("unroll") for (int ks = 0; ks < 4; ++ks)                     \
            bc[ks] = *(const bf16x8*)&Bff[lm*128 + ks*32 + kq8];             \
        _Pragma("unroll") for (int nt = 0; nt < 8; ++nt) {                   \
            if (nt < 7)                                                      \
                _Pragma("unroll") for (int ks = 0; ks < 4; ++ks)             \
                    bn[ks] = *(const bf16x8*)&Bff[((nt+1)*16 + lm)*128       \
                                                  + ks*32 + kq8];            \
            f32x4 c = (f32x4){0.f,0.f,0.f,0.f};                              \
            _Pragma("unroll") for (int ks = 0; ks < 4; ++ks)                 \
                c = __builtin_amdgcn_mfma_f32_16x16x32_bf16(                 \
                    af[ks], bc[ks], c, 0, 0, 0);                             \
            if (q < 2)                                                       \
                _Pragma("unroll") for (int r = 0; r < 4; ++r) {              \
                    int tok = r0 + r;                                        \
                    sl[tok*128 + ((nt*16 + lm) ^ (tok<<3))] = f2bf(c[r]);    \
                }                                                            \
            _Pragma("unroll") for (int ks = 0; ks < 4; ++ks) bc[ks] = bn[ks];\
        }                                                                    \
    }
// f=32 slice: compute + write (A-frags pre-read before a barrier), nt = wave
#define PHASE_B32(base, AF)                                                  \
    {   f32x4 c = (f32x4){0.f,0.f,0.f,0.f};                                  \
        _Pragma("unroll") for (int ks = 0; ks < 4; ++ks)                     \
            c = __builtin_amdgcn_mfma_f32_16x16x32_bf16(                     \
                AF[ks], bq32[ks], c, 0, 0, 0);                               \
        if (q < 2)                                                           \
            _Pragma("unroll") for (int r = 0; r < 4; ++r) {                  \
                int tok = r0 + r;                                            \
                sm[(base) + 32*SF + tok*128 + ((wave*16 + lm) ^ (tok<<3))]   \
                    = f2bf(c[r]);                                            \
            }                                                                \
    }
#define PHASE_C(base, tile)                                                  \
    _Pragma("unroll") for (int nt = 0; nt < 4; ++nt) {                       \
        const int o = nt*16 + lm;                                            \
        const int cb = wave*128 + ((2*o) ^ (wave<<3));                       \
        f32x4 acc[4];                                                        \
        _Pragma("unroll") for (int mt = 0; mt < 4; ++mt)                     \
            acc[mt] = (f32x4){0.f,0.f,0.f,0.f};                              \
        _Pragma("unroll") for (int kt = 0; kt < 3; ++kt) {                   \
            union { u32 w[4]; bf16x8 v; } bq;                                \
            _Pragma("unroll") for (int j = 0; j < 4; ++j) {                  \
                int f = kt*16 + q*4 + j;                                     \
                u32 vv = 0u;                                                 \
                if (f < 33) vv = *(const u32*)&sm[(base) + f*SF + cb];       \
                bq.w[j] = vv;                                                \
            }                                                                \
            _Pragma("unroll") for (int mt = 0; mt < 4; ++mt)                 \
                acc[mt] = __builtin_amdgcn_mfma_f32_16x16x32_bf16(           \
                    ef[kt][mt], bq.v, acc[mt], 0, 0, 0);                     \
        }                                                                    \
        float* yb = y + ((size_t)(blockIdx.x*16 + (tile)*8 + wave))*4096     \
                      + o*64;                                                \
        _Pragma("unroll") for (int mt = 0; mt < 4; ++mt) {                   \
            float4 st = { acc[mt][0], acc[mt][1], acc[mt][2], acc[mt][3] };  \
            *(float4*)&yb[mt*16 + r0] = st;                                  \
        }                                                                    \
    }

    // hoists: DFT basis frags, iDFT basis frags, f=32 B-operand (all L2-hot)
    bf16x8 bfr[2][5];
#pragma unroll
    for (int kt = 0; kt < 2; ++kt)
#pragma unroll
        for (int ni = 0; ni < 5; ++ni)
            bfr[kt][ni] = *(const bf16x8*)&Dt[((kt*4 + q)*80 + ni*16 + lm)*8];
    bf16x8 ef[3][4];
#pragma unroll
    for (int kt = 0; kt < 3; ++kt)
#pragma unroll
        for (int mt = 0; mt < 4; ++mt)
            ef[kt][mt] = *(const bf16x8*)&E2[((kt*4 + q)*64 + mt*16 + lm)*8];
    bf16x8 bq32[4];
#pragma unroll
    for (int ks = 0; ks < 4; ++ks)
        bq32[ks] = *(const bf16x8*)&Bf[(size_t)32*16384
                                       + (wave*16 + lm)*128 + ks*32 + kq8];

    // ---- A0: DFT tile 0 ----------------------------------------------------
    {
        float4 xv[2][4][2];
        LOADX(xv, 0)
        f32x4 acc[4][5];
#pragma unroll
        for (int mi = 0; mi < 4; ++mi)
#pragma unroll
            for (int ni = 0; ni < 5; ++ni) acc[mi][ni] = (f32x4){0.f,0.f,0.f,0.f};
        A_MFMA(xv, acc)
        SCATTER(acc, 0)
    }
    __syncthreads();                       // bar1: XF0 complete
    bf16x8 af32a[4];
#pragma unroll
    for (int ks = 0; ks < 4; ++ks)         // f=32 A-frags (all waves read)
        af32a[ks] = *(const bf16x8*)&sm[32*SF + (lm&7)*128
                                        + ((ks*32 + kq8) ^ ((lm&7)<<3))];
    __syncthreads();                       // bar2: f32 reads precede B0 writes

    // ---- B0 with A1's x-loads in flight ------------------------------------
    float4 xv1[2][4][2];
    LOADX(xv1, 1)                          // 16 HBM loads issued...
    asm volatile("" ::: "memory");         // ...pinned before B0 (compiler fence)
    PHASE_B(0)
    PHASE_B32(0, af32a)
    {   // A1 compute + scatter into sm[1] (disjoint from B0's sm[0])
        f32x4 acc[4][5];
#pragma unroll
        for (int mi = 0; mi < 4; ++mi)
#pragma unroll
            for (int ni = 0; ni < 5; ++ni) acc[mi][ni] = (f32x4){0.f,0.f,0.f,0.f};
        A_MFMA(xv1, acc)
        SCATTER(acc, TILE_ELEMS)
    }
    __syncthreads();                       // bar3: YF0 + XF1 complete
    bf16x8 af32b[4];
#pragma unroll
    for (int ks = 0; ks < 4; ++ks)
        af32b[ks] = *(const bf16x8*)&sm[TILE_ELEMS + 32*SF + (lm&7)*128
                                        + ((ks*32 + kq8) ^ ((lm&7)<<3))];
    __syncthreads();                       // bar4: f32 reads precede B1 writes

    // ---- C0 (stores drain async) then B1 (L2 under the store shadow) -------
    PHASE_C(0, 0)
    PHASE_B(TILE_ELEMS)
    PHASE_B32(TILE_ELEMS, af32b)
    __syncthreads();                       // bar5: YF1 complete
    PHASE_C(TILE_ELEMS, 1)
}

extern "C" void kernel_launch(void* const* d_in, const int* in_sizes, int n_in,
                              void* d_out, int out_size, void* d_ws, size_t ws_size,
                              hipStream_t stream) {
    const float* x      = (const float*)d_in[0];  // (2,2048,4096) fp32
    const float* params = (const float*)d_in[1];  // (4,64,64,64)  fp32
    const float* cw     = (const float*)d_in[2];  // (4,)          fp32
    float* out = (float*)d_out;

    u16* Bf = (u16*)d_ws;
    u16* Dt = Bf + DT_OFF;
    u16* Eg = Bf + E_OFF;

    prep<<<1025, 256, 0, stream>>>(params, cw, Bf, Dt, Eg);
    fused<<<256, 512, 0, stream>>>(x, Dt, Bf, Eg, out);
}

// Round 10
// 161.838 us; speedup vs baseline: 1.6039x; 1.2879x over previous
//
#include <hip/hip_runtime.h>
#include <math.h>

// FFTChainMatrix, fully fused frequency-domain factorization.
//   prep : build Bf (33 x 128 x 128 combined spectral operator), Dt2 (DFT
//          basis, fragment-major), E2 (iDFT basis, fragment-major).
//   fused: 256 blocks x 512 thr (8 waves), 16 tokens/block, all in LDS:
//     A: XF[f][tok][2i+par] = rfft_64(x blocks)        (MFMA, K=64, N=66)
//     B: per f: YF = XF . Bf[f]^T, in place in LDS     (MFMA, M=16,N=128,K=128)
//     C: y = E . YF  gathered across f slices          (MFMA, M=64,N=128,K=96)
// v10 = verbatim revert to the round-1 kernel (65.5us fused, best measured).
// Session ledger: TLP (v2), 2-blk co-residency (v3), compiler ILP (v4), and
// register pipelines (v7/v9) ALL regressed; v7/v9 proved the compiler pins
// VGPR at 128 here and spills any cross-phase prefetch (53MB scratch traffic).
// This configuration is the verified local optimum for this toolchain.

typedef unsigned short u16;
typedef unsigned int   u32;
typedef __attribute__((ext_vector_type(8))) short bf16x8;
typedef __attribute__((ext_vector_type(4))) float f32x4;

#define TWO_PI 6.2831853071795864769f

#define SF 2056                          // u16 per f-slice in LDS (2048 + 8 pad)
                                         // SF/2 = 1028 dw == +4 banks per f
#define BF_ELEMS (33u*128u*128u)         // 540672 u16
#define DT_OFF   BF_ELEMS
#define DT_ELEMS (2u*4u*80u*8u)          // 5120  : [kt][q][n(80)][8]
#define E_OFF    (DT_OFF + DT_ELEMS)
#define E_ELEMS  (3u*4u*64u*8u)          // 6144  : [kt][q][t(64)][8]

__device__ __forceinline__ u16 f2bf(float f) {   // RNE fp32 -> bf16
    union { float f; unsigned u; } v; v.f = f;
    unsigned r = v.u + 0x7FFFu + ((v.u >> 16) & 1u);
    return (u16)(r >> 16);
}

// ---- prep: block 0 -> Dt2/E2 tables; blocks 1..1024 -> Bf ------------------
__global__ void prep(const float* __restrict__ p, const float* __restrict__ cw,
                     u16* __restrict__ Bf, u16* __restrict__ Dt, u16* __restrict__ E) {
    const int tid = threadIdx.x;
    if (blockIdx.x == 0) {
        // Dt2[((kt*4+q)*80 + n)*8 + j] = basis(n, k=kt*32+q*8+j), 16B frags
        for (int e = tid; e < (int)DT_ELEMS; e += 256) {
            int j = e & 7, rowid = e >> 3;
            int n = rowid % 80, grp = rowid / 80;          // grp = kt*4+q
            int k = (grp >> 2) * 32 + (grp & 3) * 8 + j;
            float v = 0.f;
            if (n < 66) {
                int f = n >> 1;
                float ang = TWO_PI * (float)((f * k) & 63) * (1.f / 64.f);
                v = (n & 1) ? -sinf(ang) : cosf(ang);
            }
            Dt[e] = f2bf(v);
        }
        // E2[((kt*4+q)*64 + t)*8 + j] = ibasis(t, k=kt*32+q*8+j), zeros for k>=66
        for (int e = tid; e < (int)E_ELEMS; e += 256) {
            int j = e & 7, rowid = e >> 3;
            int t = rowid % 64, grp = rowid / 64;          // grp = kt*4+q
            int k = (grp >> 2) * 32 + (grp & 3) * 8 + j;
            float v = 0.f;
            if (k < 66) {
                int f = k >> 1;
                float wf = (f == 0 || f == 32) ? 1.f : 2.f;
                float ang = TWO_PI * (float)((f * t) & 63) * (1.f / 64.f);
                v = (wf * (1.f / 64.f)) * ((k & 1) ? -sinf(ang) : cosf(ang));
            }
            E[e] = f2bf(v);
        }
        return;
    }
    // Bf: 4 (o,i) pairs per block (layout: [f][n=2o+par][k=2i+par])
    __shared__ float  ct[4][64];
    __shared__ float2 trig[64];
    const int pr = tid >> 6, ln = tid & 63;
    if (tid < 64) {
        float s, c;
        sincosf(TWO_PI * (float)tid * (1.f / 64.f), &s, &c);
        trig[tid] = make_float2(s, c);
    }
    const int pg = (blockIdx.x - 1) * 4 + pr;     // 0..4095
    const int o = pg >> 6, i = pg & 63;
    {
        const float* base = p + (size_t)o * 4096 + i * 64 + ln;
        ct[pr][ln] = cw[0] * base[0]      + cw[1] * base[262144]
                   + cw[2] * base[524288] + cw[3] * base[786432];
    }
    __syncthreads();
    if (ln < 33) {        // f = ln
        float cr = 0.f, ci = 0.f;
        for (int u = 0; u < 64; ++u) {
            float2 sc = trig[(ln * u) & 63];
            cr += ct[pr][u] * sc.y; ci -= ct[pr][u] * sc.x;
        }
        u16* b = Bf + (size_t)ln * 16384 + (2 * o) * 128 + 2 * i;
        b[0]   = f2bf(cr);  b[1]   = f2bf(-ci);
        b[128] = f2bf(ci);  b[129] = f2bf(cr);
    }
}

// ---- fused: DFT -> per-f GEMM -> iDFT, one block = 16 tokens ---------------
__global__ __launch_bounds__(512) void fused(const float* __restrict__ x,
                                             const u16* __restrict__ Dt,
                                             const u16* __restrict__ Bf,
                                             const u16* __restrict__ E2,
                                             float* __restrict__ y) {
    __shared__ u16 sm[33 * SF];          // 135,696 B
    const int tid = threadIdx.x, lane = tid & 63, wave = tid >> 6;
    const int lm = lane & 15, q = lane >> 4, kq8 = q * 8, r0 = q * 4;
    const float* xb = x + (size_t)blockIdx.x * (16u * 4096u);

    // -------- phase A: DFT, XF[f][tok][(2i+par)^((tok&7)<<3)] --------------
#pragma unroll
    for (int pass = 0; pass < 2; ++pass) {
        f32x4 acc[4][5];
#pragma unroll
        for (int mi = 0; mi < 4; ++mi)
#pragma unroll
            for (int ni = 0; ni < 5; ++ni) acc[mi][ni] = (f32x4){0.f,0.f,0.f,0.f};
#pragma unroll
        for (int kt = 0; kt < 2; ++kt) {
            bf16x8 bfr[5];
#pragma unroll
            for (int ni = 0; ni < 5; ++ni)      // Dt2 is L2-hot, 16B frags
                bfr[ni] = *(const bf16x8*)&Dt[((kt*4 + q)*80 + ni*16 + lm)*8];
#pragma unroll
            for (int mi = 0; mi < 4; ++mi) {
                const int row = wave*128 + pass*64 + mi*16 + lm;  // (tok,i)
                const float* rp = xb + row*64 + kt*32 + kq8;
                float4 p0 = *(const float4*)rp;
                float4 p1 = *(const float4*)(rp + 4);
                union { u16 u[8]; bf16x8 v; } pk;
                pk.u[0]=f2bf(p0.x); pk.u[1]=f2bf(p0.y);
                pk.u[2]=f2bf(p0.z); pk.u[3]=f2bf(p0.w);
                pk.u[4]=f2bf(p1.x); pk.u[5]=f2bf(p1.y);
                pk.u[6]=f2bf(p1.z); pk.u[7]=f2bf(p1.w);
#pragma unroll
                for (int ni = 0; ni < 5; ++ni)
                    acc[mi][ni] = __builtin_amdgcn_mfma_f32_16x16x32_bf16(
                        pk.v, bfr[ni], acc[mi][ni], 0, 0, 0);
            }
        }
        // scatter C into XF slices (bf16), XOR row-swizzle
#pragma unroll
        for (int mi = 0; mi < 4; ++mi)
#pragma unroll
            for (int ni = 0; ni < 5; ++ni) {
                const int col = ni*16 + lm;
                if (col < 66) {
                    const int f = col >> 1, par = col & 1;
                    const int mb = wave*128 + pass*64 + mi*16 + r0;
                    f32x4 v = acc[mi][ni];
#pragma unroll
                    for (int r = 0; r < 4; ++r) {
                        int m = mb + r, tok = m >> 6, ii = m & 63;
                        sm[f*SF + tok*128 + (((ii<<1)|par) ^ ((tok&7)<<3))] = f2bf(v[r]);
                    }
                }
            }
    }
    __syncthreads();

    // -------- phase B: per f, YF = XF . Bf[f]^T, in place (f per wave) -----
    for (int f = wave; f < 33; f += 8) {
        u16* sl = &sm[f * SF];
        const u16* Bff = Bf + (size_t)f * 16384;
        bf16x8 af[4];                       // full A (M=16) in regs first
#pragma unroll
        for (int ks = 0; ks < 4; ++ks)
            af[ks] = *(const bf16x8*)&sl[lm*128 + ((ks*32 + kq8) ^ ((lm&7)<<3))];
#pragma unroll
        for (int nt = 0; nt < 8; ++nt) {
            f32x4 c = (f32x4){0.f,0.f,0.f,0.f};
#pragma unroll
            for (int ks = 0; ks < 4; ++ks) {  // Bf fragments straight from L2
                bf16x8 bq = *(const bf16x8*)&Bff[(nt*16 + lm)*128 + ks*32 + kq8];
                c = __builtin_amdgcn_mfma_f32_16x16x32_bf16(af[ks], bq, c, 0, 0, 0);
            }
#pragma unroll
            for (int r = 0; r < 4; ++r) {     // write-back: cols nt*16+lm
                int tok = r0 + r;
                sl[tok*128 + ((nt*16 + lm) ^ ((tok&7)<<3))] = f2bf(c[r]);
            }
        }
    }
    __syncthreads();

    // -------- phase C: y = E . YF (A=E so stores are float4 over t) --------
    bf16x8 ef[3][4];
#pragma unroll
    for (int kt = 0; kt < 3; ++kt)
#pragma unroll
        for (int mt = 0; mt < 4; ++mt)        // E2 is L1-resident (12 KB)
            ef[kt][mt] = *(const bf16x8*)&E2[((kt*4 + q)*64 + mt*16 + lm)*8];
#pragma unroll
    for (int nt = 0; nt < 8; ++nt) {          // 128 (tok,o) rows per wave
        const int tokL = wave*2 + (nt >> 2);
        const int o = (nt & 3)*16 + lm;
        const int cb = tokL*128 + ((2*o) ^ ((tokL&7)<<3));
        f32x4 acc[4];
#pragma unroll
        for (int mt = 0; mt < 4; ++mt) acc[mt] = (f32x4){0.f,0.f,0.f,0.f};
#pragma unroll
        for (int kt = 0; kt < 3; ++kt) {
            union { u32 w[4]; bf16x8 v; } bq;  // (re,im) pairs across f slices
#pragma unroll
            for (int j = 0; j < 4; ++j) {
                int f = kt*16 + q*4 + j;
                u32 vv = 0u;
                if (f < 33) vv = *(const u32*)&sm[f*SF + cb];
                bq.w[j] = vv;
            }
#pragma unroll
            for (int mt = 0; mt < 4; ++mt)
                acc[mt] = __builtin_amdgcn_mfma_f32_16x16x32_bf16(
                    ef[kt][mt], bq.v, acc[mt], 0, 0, 0);
        }
        float* yb = y + ((size_t)(blockIdx.x*16 + tokL))*4096 + o*64;
#pragma unroll
        for (int mt = 0; mt < 4; ++mt) {       // 4 consecutive t per lane
            float4 st = { acc[mt][0], acc[mt][1], acc[mt][2], acc[mt][3] };
            *(float4*)&yb[mt*16 + r0] = st;
        }
    }
}

extern "C" void kernel_launch(void* const* d_in, const int* in_sizes, int n_in,
                              void* d_out, int out_size, void* d_ws, size_t ws_size,
                              hipStream_t stream) {
    const float* x      = (const float*)d_in[0];  // (2,2048,4096) fp32
    const float* params = (const float*)d_in[1];  // (4,64,64,64)  fp32
    const float* cw     = (const float*)d_in[2];  // (4,)          fp32
    float* out = (float*)d_out;

    u16* XF = (u16*)d_ws;                          // unused scratch naming kept
    u16* Bf = XF;
    u16* Dt = Bf + DT_OFF;
    u16* Eg = Bf + E_OFF;

    prep<<<1025, 256, 0, stream>>>(params, cw, Bf, Dt, Eg);
    fused<<<256, 512, 0, stream>>>(x, Dt, Bf, Eg, out);
}